// Round 1
// baseline (1341.889 us; speedup 1.0000x reference)
//
#include <hip/hip_runtime.h>
#include <hip/hip_bf16.h>
#include <math.h>

// Problem constants (fixed by setup_inputs)
#define NB 4
#define LQ 300
#define CDIM 256
#define NH 8
#define DH 32
#define NL 4
#define NP 4
#define ROI_ 7
#define LEN_IN 19947
#define H0 100
#define W0 150
#define ROI_DIM (ROI_*ROI_*CDIM)   // 12544
#define NQ_TOT (NB*LQ)             // 1200
#define QPB 3                      // queries per block in K2

__device__ __constant__ int d_HL[4] = {100, 50, 25, 13};
__device__ __constant__ int d_WL[4] = {150, 75, 38, 19};
__device__ __constant__ int d_ST[4] = {0, 15000, 18750, 19700};

// ---------------- K1: value = input_flatten @ Wv + bv, masked ----------------
__global__ __launch_bounds__(256) void k_value_proj(
    const float* __restrict__ inp,            // (NB*LEN_IN, 256)
    const unsigned char* __restrict__ mask,   // (NB*LEN_IN)
    const float* __restrict__ Wv,             // (256,256)
    const float* __restrict__ bv,             // (256)
    float* __restrict__ value)                // (NB*LEN_IN, 256)
{
    const int ROWS = 16;
    __shared__ float a_s[ROWS][CDIM];
    const int total = NB * LEN_IN;
    int row0 = blockIdx.x * ROWS;
    int tid = threadIdx.x;

    #pragma unroll
    for (int r = 0; r < ROWS; ++r) {
        int row = row0 + r;
        a_s[r][tid] = (row < total) ? inp[(size_t)row * CDIM + tid] : 0.f;
    }
    __syncthreads();

    float acc[ROWS];
    #pragma unroll
    for (int r = 0; r < ROWS; ++r) acc[r] = 0.f;

    for (int k = 0; k < CDIM; ++k) {
        float w = Wv[k * CDIM + tid];
        #pragma unroll
        for (int r = 0; r < ROWS; ++r) acc[r] += a_s[r][k] * w;
    }

    float b = bv[tid];
    #pragma unroll
    for (int r = 0; r < ROWS; ++r) {
        int row = row0 + r;
        if (row < total) {
            float v = acc[r] + b;
            if (mask[row]) v = 0.f;
            value[(size_t)row * CDIM + tid] = v;
        }
    }
}

// ------- K2: fused ROI-align (level 0) + [Wp|Ww] GEMM + tanh + softmax -------
__global__ __launch_bounds__(384) void k_roi_gemm(
    const float* __restrict__ value,   // (NB, LEN_IN, 256)
    const float* __restrict__ refp,    // (NB, LQ, 4, 4)
    const float* __restrict__ Wp,      // (12544, 256)
    const float* __restrict__ bp,      // (256)
    const float* __restrict__ Ww,      // (12544, 128)
    const float* __restrict__ bw,      // (128)
    float* __restrict__ pr_out,        // (1200, 256)  tanh'd offsets
    float* __restrict__ attn_out)      // (1200, 128)  softmax'd weights
{
    __shared__ float roi_s[QPB][ROI_DIM];     // 3 * 50176 B
    __shared__ float logit_s[QPB][128];

    int tid = threadIdx.x;
    int nq0 = blockIdx.x * QPB;

    // ---- phase 1: ROI align into LDS ----
    for (int qi = 0; qi < QPB; ++qi) {
        int nq = nq0 + qi;
        int n = nq / LQ, q = nq % LQ;
        const float* rp = refp + (((size_t)(n * LQ + q)) * NL + 0) * 4;
        float cx = rp[0], cy = rp[1], w = rp[2], h = rp[3];
        float x1 = (cx - 0.5f * w) * W0 - 0.5f;
        float y1 = (cy - 0.5f * h) * H0 - 0.5f;
        float binw = w * W0 / ROI_;
        float binh = h * H0 / ROI_;
        const float* v0 = value + (size_t)n * LEN_IN * CDIM;

        for (int e = tid; e < ROI_DIM; e += 384) {
            int p = e >> 8;        // 0..48
            int ch = e & 255;
            int r = p / ROI_, c = p % ROI_;
            float sy = y1 + binh * (r + 0.5f);
            float sx = x1 + binw * (c + 0.5f);
            float y0f = floorf(sy), x0f = floorf(sx);
            float wy1 = sy - y0f, wx1 = sx - x0f;
            int y0 = (int)y0f, x0 = (int)x0f;
            float acc = 0.f;
            #pragma unroll
            for (int dy = 0; dy <= 1; ++dy) {
                #pragma unroll
                for (int dx = 0; dx <= 1; ++dx) {
                    int yy = y0 + dy, xx = x0 + dx;
                    if (yy >= 0 && yy < H0 && xx >= 0 && xx < W0) {
                        float wgt = (dy ? wy1 : 1.f - wy1) * (dx ? wx1 : 1.f - wx1);
                        acc += wgt * v0[((size_t)(yy * W0 + xx)) * CDIM + ch];
                    }
                }
            }
            roi_s[qi][e] = acc;
        }
    }
    __syncthreads();

    // ---- phase 2: GEMM: 384 output cols (256 -> Wp, 128 -> Ww) ----
    int col = tid;
    const float* Wsel;
    int stride;
    float bias;
    if (col < 256) { Wsel = Wp + col;         stride = 256; bias = bp[col]; }
    else           { Wsel = Ww + (col - 256); stride = 128; bias = bw[col - 256]; }

    float acc0 = 0.f, acc1 = 0.f, acc2 = 0.f;
    const float* wptr = Wsel;
    #pragma unroll 8
    for (int k = 0; k < ROI_DIM; ++k) {
        float wv = *wptr; wptr += stride;
        acc0 += roi_s[0][k] * wv;
        acc1 += roi_s[1][k] * wv;
        acc2 += roi_s[2][k] * wv;
    }
    acc0 += bias; acc1 += bias; acc2 += bias;

    if (col < 256) {
        pr_out[(size_t)(nq0 + 0) * 256 + col] = tanhf(acc0);
        pr_out[(size_t)(nq0 + 1) * 256 + col] = tanhf(acc1);
        pr_out[(size_t)(nq0 + 2) * 256 + col] = tanhf(acc2);
    } else {
        int j = col - 256;
        logit_s[0][j] = acc0;
        logit_s[1][j] = acc1;
        logit_s[2][j] = acc2;
    }
    __syncthreads();

    // ---- phase 3: softmax over groups of 16 (per query, per head) ----
    // 24 groups (QPB*NH) x 16 lanes = 384 threads exactly
    {
        int i = tid & 15;
        int g = tid >> 4;          // 0..23
        int qi = g >> 3, h = g & 7;
        float v = logit_s[qi][h * 16 + i];
        float m = v;
        #pragma unroll
        for (int off = 8; off >= 1; off >>= 1)
            m = fmaxf(m, __shfl_xor(m, off, 16));
        float e = expf(v - m);
        float s = e;
        #pragma unroll
        for (int off = 8; off >= 1; off >>= 1)
            s += __shfl_xor(s, off, 16);
        attn_out[(size_t)(nq0 + qi) * 128 + h * 16 + i] = e / s;
    }
}

// --------- K3: multi-scale deformable sampling + weighted sum ----------
__global__ __launch_bounds__(256) void k_sample(
    const float* __restrict__ value,   // (NB, LEN_IN, 256)
    const float* __restrict__ refp,    // (NB, LQ, 4, 4)
    const float* __restrict__ pr,      // (1200, 256)
    const float* __restrict__ attn,    // (1200, 128)
    float* __restrict__ out_attn)      // (1200, 256)
{
    int nq = blockIdx.x;
    int n = nq / LQ;
    int tid = threadIdx.x;
    int h = tid >> 5, dh = tid & 31;

    float acc = 0.f;
    for (int l = 0; l < NL; ++l) {
        const float* rp = refp + ((size_t)nq * NL + l) * 4;
        float cx = rp[0], cy = rp[1], rw = rp[2], rh = rp[3];
        int Hl = d_HL[l], Wl = d_WL[l], s = d_ST[l];
        const float* vl = value + ((size_t)n * LEN_IN + s) * CDIM;

        #pragma unroll
        for (int p = 0; p < NP; ++p) {
            float prx = pr[(size_t)nq * 256 + h * 32 + l * 8 + p * 2 + 0];
            float pry = pr[(size_t)nq * 256 + h * 32 + l * 8 + p * 2 + 1];
            float a   = attn[(size_t)nq * 128 + h * 16 + l * 4 + p];
            float px = (cx + prx * rw * 0.5f) * Wl - 0.5f;
            float py = (cy + pry * rh * 0.5f) * Hl - 0.5f;
            float x0f = floorf(px), y0f = floorf(py);
            float wx1 = px - x0f, wy1 = py - y0f;
            int x0 = (int)x0f, y0 = (int)y0f;
            float sv = 0.f;
            #pragma unroll
            for (int dy = 0; dy <= 1; ++dy) {
                #pragma unroll
                for (int dx = 0; dx <= 1; ++dx) {
                    int yy = y0 + dy, xx = x0 + dx;
                    if (yy >= 0 && yy < Hl && xx >= 0 && xx < Wl) {
                        float wgt = (dy ? wy1 : 1.f - wy1) * (dx ? wx1 : 1.f - wx1);
                        sv += wgt * vl[((size_t)(yy * Wl + xx)) * CDIM + h * 32 + dh];
                    }
                }
            }
            acc += a * sv;
        }
    }
    out_attn[(size_t)nq * CDIM + tid] = acc;
}

// ---------------- K4: out = out_attn @ Wo + bo ----------------
__global__ __launch_bounds__(256) void k_out_proj(
    const float* __restrict__ x,       // (1200, 256)
    const float* __restrict__ Wo,      // (256, 256)
    const float* __restrict__ bo,      // (256)
    float* __restrict__ out)           // (1200, 256)
{
    const int ROWS = 8;
    __shared__ float a_s[ROWS][CDIM];
    int row0 = blockIdx.x * ROWS;
    int tid = threadIdx.x;

    #pragma unroll
    for (int r = 0; r < ROWS; ++r)
        a_s[r][tid] = x[(size_t)(row0 + r) * CDIM + tid];
    __syncthreads();

    float acc[ROWS];
    #pragma unroll
    for (int r = 0; r < ROWS; ++r) acc[r] = 0.f;

    for (int k = 0; k < CDIM; ++k) {
        float w = Wo[k * CDIM + tid];
        #pragma unroll
        for (int r = 0; r < ROWS; ++r) acc[r] += a_s[r][k] * w;
    }
    float b = bo[tid];
    #pragma unroll
    for (int r = 0; r < ROWS; ++r)
        out[(size_t)(row0 + r) * CDIM + tid] = acc[r] + b;
}

extern "C" void kernel_launch(void* const* d_in, const int* in_sizes, int n_in,
                              void* d_out, int out_size, void* d_ws, size_t ws_size,
                              hipStream_t stream) {
    // inputs (setup_inputs order):
    // 0 query (unused), 1 reference_points, 2 input_flatten, 3 shapes (unused),
    // 4 starts (unused), 5 padding_mask, 6 Wv, 7 bv, 8 Wp, 9 bp, 10 Ww, 11 bw, 12 Wo, 13 bo
    const float* refp = (const float*)d_in[1];
    const float* inp  = (const float*)d_in[2];
    const unsigned char* mask = (const unsigned char*)d_in[5];
    const float* Wv = (const float*)d_in[6];
    const float* bv = (const float*)d_in[7];
    const float* Wp = (const float*)d_in[8];
    const float* bp = (const float*)d_in[9];
    const float* Ww = (const float*)d_in[10];
    const float* bw = (const float*)d_in[11];
    const float* Wo = (const float*)d_in[12];
    const float* bo = (const float*)d_in[13];
    float* out = (float*)d_out;

    // workspace layout
    char* ws = (char*)d_ws;
    constexpr size_t VALUE_BYTES = (size_t)NB * LEN_IN * CDIM * 4;   // 81,702,912
    constexpr size_t PR_BYTES    = (size_t)NQ_TOT * 256 * 4;          // 1,228,800
    constexpr size_t ATTN_BYTES  = (size_t)NQ_TOT * 128 * 4;          //   614,400
    float* value    = (float*)ws;
    float* pr       = (float*)(ws + VALUE_BYTES);
    float* attn     = (float*)(ws + VALUE_BYTES + PR_BYTES);
    float* out_attn = (float*)(ws + VALUE_BYTES + PR_BYTES + ATTN_BYTES);

    // K1: value projection. 79788 rows, 16/block
    {
        int total = NB * LEN_IN;
        int grid = (total + 15) / 16;
        k_value_proj<<<grid, 256, 0, stream>>>(inp, mask, Wv, bv, value);
    }
    // K2: ROI + Wp/Ww GEMM + tanh/softmax. 1200/3 = 400 blocks
    {
        k_roi_gemm<<<NQ_TOT / QPB, 384, 0, stream>>>(value, refp, Wp, bp, Ww, bw, pr, attn);
    }
    // K3: deformable sampling. 1200 blocks
    {
        k_sample<<<NQ_TOT, 256, 0, stream>>>(value, refp, pr, attn, out_attn);
    }
    // K4: output projection. 150 blocks
    {
        k_out_proj<<<NQ_TOT / 8, 256, 0, stream>>>(out_attn, Wo, bo, out);
    }
}

// Round 2
// 399.428 us; speedup vs baseline: 3.3595x; 3.3595x over previous
//
#include <hip/hip_runtime.h>
#include <hip/hip_bf16.h>
#include <math.h>

// Problem constants (fixed by setup_inputs)
#define NB 4
#define LQ 300
#define CDIM 256
#define NH 8
#define DH 32
#define NL 4
#define NP 4
#define ROI_ 7
#define LEN_IN 19947
#define H0 100
#define W0 150
#define ROI_DIM (ROI_*ROI_*CDIM)   // 12544
#define NQ_TOT (NB*LQ)             // 1200
#define QPB 3                      // queries per block in fallback K2

// GEMM (K2b) config
#define MPAD 1216                  // 19 * 64
#define NDIM 384
#define GSEG 7                     // split-K segments
#define GCH  28                    // K-chunks (of 64) per segment: 7*28*64 = 12544

__device__ __constant__ int d_HL[4] = {100, 50, 25, 13};
__device__ __constant__ int d_WL[4] = {150, 75, 38, 19};
__device__ __constant__ int d_ST[4] = {0, 15000, 18750, 19700};

typedef __attribute__((ext_vector_type(8))) short short8;
typedef __attribute__((ext_vector_type(4))) float f32x4;

__device__ __forceinline__ unsigned short f2bf(float f) {
    unsigned int u = __float_as_uint(f);
    unsigned int r = (u + 0x7fffu + ((u >> 16) & 1u)) >> 16;
    return (unsigned short)r;
}
__device__ __forceinline__ float bf2f(unsigned short s) {
    return __uint_as_float(((unsigned int)s) << 16);
}

// ---------------- K1: value = input_flatten @ Wv + bv, masked ----------------
__global__ __launch_bounds__(256) void k_value_proj(
    const float* __restrict__ inp,            // (NB*LEN_IN, 256)
    const unsigned char* __restrict__ mask,   // (NB*LEN_IN)
    const float* __restrict__ Wv,             // (256,256)
    const float* __restrict__ bv,             // (256)
    float* __restrict__ value)                // (NB*LEN_IN, 256)
{
    const int ROWS = 16;
    __shared__ float a_s[ROWS][CDIM];
    const int total = NB * LEN_IN;
    int row0 = blockIdx.x * ROWS;
    int tid = threadIdx.x;

    #pragma unroll
    for (int r = 0; r < ROWS; ++r) {
        int row = row0 + r;
        a_s[r][tid] = (row < total) ? inp[(size_t)row * CDIM + tid] : 0.f;
    }
    __syncthreads();

    float acc[ROWS];
    #pragma unroll
    for (int r = 0; r < ROWS; ++r) acc[r] = 0.f;

    for (int k = 0; k < CDIM; k += 4) {
        float w0 = Wv[(k + 0) * CDIM + tid];
        float w1 = Wv[(k + 1) * CDIM + tid];
        float w2 = Wv[(k + 2) * CDIM + tid];
        float w3 = Wv[(k + 3) * CDIM + tid];
        #pragma unroll
        for (int r = 0; r < ROWS; ++r) {
            float4 av = *(const float4*)&a_s[r][k];
            acc[r] = fmaf(av.x, w0, fmaf(av.y, w1, fmaf(av.z, w2, fmaf(av.w, w3, acc[r]))));
        }
    }

    float b = bv[tid];
    #pragma unroll
    for (int r = 0; r < ROWS; ++r) {
        int row = row0 + r;
        if (row < total) {
            float v = acc[r] + b;
            if (mask[row]) v = 0.f;
            value[(size_t)row * CDIM + tid] = v;
        }
    }
}

// -------- K2a: ROI-align (level 0) -> roi_hi / roi_lo (bf16 split) ----------
__global__ __launch_bounds__(256) void k_roi_split(
    const float* __restrict__ value,   // (NB, LEN_IN, 256)
    const float* __restrict__ refp,    // (NB, LQ, 4, 4)
    unsigned short* __restrict__ roiH, // (MPAD, 12544)
    unsigned short* __restrict__ roiL) // (MPAD, 12544)
{
    int q = blockIdx.x;                // 0..MPAD-1
    int tid = threadIdx.x;             // channel
    if (q >= NQ_TOT) {                 // zero pad rows (ws is poisoned)
        for (int i = 0; i < 49; ++i) {
            roiH[(size_t)q * ROI_DIM + i * 256 + tid] = 0;
            roiL[(size_t)q * ROI_DIM + i * 256 + tid] = 0;
        }
        return;
    }
    int n = q / LQ;
    const float* rp = refp + (size_t)q * NL * 4;   // level 0
    float cx = rp[0], cy = rp[1], w = rp[2], h = rp[3];
    float x1 = (cx - 0.5f * w) * W0 - 0.5f;
    float y1 = (cy - 0.5f * h) * H0 - 0.5f;
    float binw = w * W0 / ROI_;
    float binh = h * H0 / ROI_;
    const float* v0 = value + (size_t)n * LEN_IN * CDIM;

    for (int i = 0; i < 49; ++i) {     // p = i, ch = tid -> e = i*256 + tid
        int r = i / ROI_, c = i % ROI_;
        float sy = y1 + binh * (r + 0.5f);
        float sx = x1 + binw * (c + 0.5f);
        float y0f = floorf(sy), x0f = floorf(sx);
        float wy1 = sy - y0f, wx1 = sx - x0f;
        int y0 = (int)y0f, x0 = (int)x0f;
        float acc = 0.f;
        #pragma unroll
        for (int dy = 0; dy <= 1; ++dy) {
            #pragma unroll
            for (int dx = 0; dx <= 1; ++dx) {
                int yy = y0 + dy, xx = x0 + dx;
                if (yy >= 0 && yy < H0 && xx >= 0 && xx < W0) {
                    float wgt = (dy ? wy1 : 1.f - wy1) * (dx ? wx1 : 1.f - wx1);
                    acc += wgt * v0[((size_t)(yy * W0 + xx)) * CDIM + tid];
                }
            }
        }
        unsigned short hb = f2bf(acc);
        float rem = acc - bf2f(hb);
        roiH[(size_t)q * ROI_DIM + i * 256 + tid] = hb;
        roiL[(size_t)q * ROI_DIM + i * 256 + tid] = f2bf(rem);
    }
}

// ------ K2w: transpose + bf16-split [Wp|Ww] (12544x384) -> WT (384x12544) ----
__global__ __launch_bounds__(256) void k_wsplit(
    const float* __restrict__ Wp,      // (12544, 256)
    const float* __restrict__ Ww,      // (12544, 128)
    unsigned short* __restrict__ WTh,  // (384, 12544)
    unsigned short* __restrict__ WTl)  // (384, 12544)
{
    __shared__ float tile[32][33];
    int k0 = blockIdx.x * 32, c0 = blockIdx.y * 32;
    int tx = threadIdx.x & 31, ty = threadIdx.x >> 5;   // 32 x 8

    #pragma unroll
    for (int i = 0; i < 4; ++i) {
        int k = k0 + ty + i * 8, c = c0 + tx;
        float v = (c < 256) ? Wp[(size_t)k * 256 + c] : Ww[(size_t)k * 128 + (c - 256)];
        tile[ty + i * 8][tx] = v;      // tile[k_local][c_local]
    }
    __syncthreads();
    #pragma unroll
    for (int i = 0; i < 4; ++i) {
        int c = c0 + ty + i * 8, k = k0 + tx;
        float v = tile[tx][ty + i * 8];
        unsigned short hb = f2bf(v);
        float rem = v - bf2f(hb);
        WTh[(size_t)c * ROI_DIM + k] = hb;
        WTl[(size_t)c * ROI_DIM + k] = f2bf(rem);
    }
}

// ------------- K2b: bf16x3 MFMA GEMM (MPAD x 384 x 12544), split-K -----------
// D layout (m89-verified): D[row=(lane>>4)*4+j][col=lane&15]
// A frag: A[row=lane&15][k=(lane>>4)*8 + j]; B frag: B[k=(lane>>4)*8+j][col=lane&15]
__global__ __launch_bounds__(256) void k_gemm_bf16x3(
    const unsigned short* __restrict__ roiH,
    const unsigned short* __restrict__ roiL,
    const unsigned short* __restrict__ WTh,
    const unsigned short* __restrict__ WTl,
    float* __restrict__ partials)      // (GSEG, MPAD, 384)
{
    __shared__ unsigned short aH[64 * 64], aL[64 * 64];     // 8KB + 8KB
    __shared__ unsigned short bH[128 * 64], bL[128 * 64];   // 16KB + 16KB
    const int mt = blockIdx.x, nt = blockIdx.y, seg = blockIdx.z;
    const int q0 = mt * 64, c0 = nt * 128;
    const int tid = threadIdx.x;
    const int lane = tid & 63;
    const int wid = tid >> 6;
    const int wm = wid >> 1, wn = wid & 1;     // wave grid 2x2, wave tile 32x64
    const int lr = lane & 15, kb = lane >> 4;

    f32x4 acc[2][4];
    #pragma unroll
    for (int i = 0; i < 2; ++i)
        #pragma unroll
        for (int j = 0; j < 4; ++j) acc[i][j] = f32x4{0.f, 0.f, 0.f, 0.f};

    const int kseg0 = seg * (GCH * 64);

    for (int ch = 0; ch < GCH; ++ch) {
        const int k0 = kseg0 + ch * 64;
        __syncthreads();
        // stage A (hi+lo): 64 rows x 8 k-octets = 512 slots, 2 per thread
        #pragma unroll
        for (int i = 0; i < 2; ++i) {
            int slot = tid + i * 256;
            int row = slot >> 3, ko = slot & 7;
            size_t g = (size_t)(q0 + row) * ROI_DIM + k0 + ko * 8;
            int off = (row * 128 + ko * 16) ^ ((row & 7) << 4);
            *(short8*)((char*)aH + off) = *(const short8*)(roiH + g);
            *(short8*)((char*)aL + off) = *(const short8*)(roiL + g);
        }
        // stage B (hi+lo): 128 cols x 8 k-octets = 1024 slots, 4 per thread
        #pragma unroll
        for (int i = 0; i < 4; ++i) {
            int slot = tid + i * 256;
            int col = slot >> 3, ko = slot & 7;
            size_t g = (size_t)(c0 + col) * ROI_DIM + k0 + ko * 8;
            int off = (col * 128 + ko * 16) ^ ((col & 7) << 4);
            *(short8*)((char*)bH + off) = *(const short8*)(WTh + g);
            *(short8*)((char*)bL + off) = *(const short8*)(WTl + g);
        }
        __syncthreads();
        #pragma unroll
        for (int kk = 0; kk < 2; ++kk) {
            short8 ah[2], al[2], bh[4], bl[4];
            #pragma unroll
            for (int i = 0; i < 2; ++i) {
                int row = wm * 32 + i * 16 + lr;
                int off = (row * 128 + (kk * 32 + kb * 8) * 2) ^ ((row & 7) << 4);
                ah[i] = *(const short8*)((const char*)aH + off);
                al[i] = *(const short8*)((const char*)aL + off);
            }
            #pragma unroll
            for (int j = 0; j < 4; ++j) {
                int col = wn * 64 + j * 16 + lr;
                int off = (col * 128 + (kk * 32 + kb * 8) * 2) ^ ((col & 7) << 4);
                bh[j] = *(const short8*)((const char*)bH + off);
                bl[j] = *(const short8*)((const char*)bL + off);
            }
            #pragma unroll
            for (int i = 0; i < 2; ++i)
                #pragma unroll
                for (int j = 0; j < 4; ++j) {
                    acc[i][j] = __builtin_amdgcn_mfma_f32_16x16x32_bf16(ah[i], bh[j], acc[i][j], 0, 0, 0);
                    acc[i][j] = __builtin_amdgcn_mfma_f32_16x16x32_bf16(ah[i], bl[j], acc[i][j], 0, 0, 0);
                    acc[i][j] = __builtin_amdgcn_mfma_f32_16x16x32_bf16(al[i], bh[j], acc[i][j], 0, 0, 0);
                }
        }
    }

    #pragma unroll
    for (int i = 0; i < 2; ++i)
        #pragma unroll
        for (int j = 0; j < 4; ++j) {
            int q = q0 + wm * 32 + i * 16 + (lane >> 4) * 4;
            int c = c0 + wn * 64 + j * 16 + lr;
            #pragma unroll
            for (int e = 0; e < 4; ++e)
                partials[((size_t)seg * MPAD + q + e) * NDIM + c] = acc[i][j][e];
        }
}

// ---------- K2c: reduce partials + bias; tanh offsets; softmax weights -------
__global__ __launch_bounds__(384) void k_epilogue(
    const float* __restrict__ partials,   // (GSEG, MPAD, 384)
    const float* __restrict__ bp, const float* __restrict__ bw,
    float* __restrict__ pr,               // (1200, 256)
    float* __restrict__ attn)             // (1200, 128)
{
    __shared__ float logit_s[128];
    int q = blockIdx.x;      // < 1200
    int t = threadIdx.x;
    float s = 0.f;
    #pragma unroll
    for (int g = 0; g < GSEG; ++g)
        s += partials[((size_t)g * MPAD + q) * NDIM + t];
    if (t < 256) {
        pr[(size_t)q * 256 + t] = tanhf(s + bp[t]);
    } else {
        logit_s[t - 256] = s + bw[t - 256];
    }
    __syncthreads();
    if (t < 128) {
        int i = t & 15;
        float v = logit_s[t];
        float m = v;
        #pragma unroll
        for (int off = 8; off >= 1; off >>= 1)
            m = fmaxf(m, __shfl_xor(m, off, 16));
        float e = expf(v - m);
        float sum = e;
        #pragma unroll
        for (int off = 8; off >= 1; off >>= 1)
            sum += __shfl_xor(sum, off, 16);
        (void)i;
        attn[(size_t)q * 128 + t] = e / sum;
    }
}

// ------- FALLBACK K2 (round-1 fused kernel) used only if ws too small -------
__global__ __launch_bounds__(384) void k_roi_gemm(
    const float* __restrict__ value,
    const float* __restrict__ refp,
    const float* __restrict__ Wp,
    const float* __restrict__ bp,
    const float* __restrict__ Ww,
    const float* __restrict__ bw,
    float* __restrict__ pr_out,
    float* __restrict__ attn_out)
{
    __shared__ float roi_s[QPB][ROI_DIM];
    __shared__ float logit_s[QPB][128];

    int tid = threadIdx.x;
    int nq0 = blockIdx.x * QPB;

    for (int qi = 0; qi < QPB; ++qi) {
        int nq = nq0 + qi;
        int n = nq / LQ;
        const float* rp = refp + (size_t)nq * NL * 4;
        float cx = rp[0], cy = rp[1], w = rp[2], h = rp[3];
        float x1 = (cx - 0.5f * w) * W0 - 0.5f;
        float y1 = (cy - 0.5f * h) * H0 - 0.5f;
        float binw = w * W0 / ROI_;
        float binh = h * H0 / ROI_;
        const float* v0 = value + (size_t)n * LEN_IN * CDIM;

        for (int e = tid; e < ROI_DIM; e += 384) {
            int p = e >> 8;
            int ch = e & 255;
            int r = p / ROI_, c = p % ROI_;
            float sy = y1 + binh * (r + 0.5f);
            float sx = x1 + binw * (c + 0.5f);
            float y0f = floorf(sy), x0f = floorf(sx);
            float wy1 = sy - y0f, wx1 = sx - x0f;
            int y0 = (int)y0f, x0 = (int)x0f;
            float acc = 0.f;
            #pragma unroll
            for (int dy = 0; dy <= 1; ++dy)
                #pragma unroll
                for (int dx = 0; dx <= 1; ++dx) {
                    int yy = y0 + dy, xx = x0 + dx;
                    if (yy >= 0 && yy < H0 && xx >= 0 && xx < W0) {
                        float wgt = (dy ? wy1 : 1.f - wy1) * (dx ? wx1 : 1.f - wx1);
                        acc += wgt * v0[((size_t)(yy * W0 + xx)) * CDIM + ch];
                    }
                }
            roi_s[qi][e] = acc;
        }
    }
    __syncthreads();

    int col = tid;
    const float* Wsel;
    int stride;
    float bias;
    if (col < 256) { Wsel = Wp + col;         stride = 256; bias = bp[col]; }
    else           { Wsel = Ww + (col - 256); stride = 128; bias = bw[col - 256]; }

    float acc0 = 0.f, acc1 = 0.f, acc2 = 0.f;
    const float* wptr = Wsel;
    #pragma unroll 8
    for (int k = 0; k < ROI_DIM; ++k) {
        float wv = *wptr; wptr += stride;
        acc0 += roi_s[0][k] * wv;
        acc1 += roi_s[1][k] * wv;
        acc2 += roi_s[2][k] * wv;
    }
    acc0 += bias; acc1 += bias; acc2 += bias;

    if (col < 256) {
        pr_out[(size_t)(nq0 + 0) * 256 + col] = tanhf(acc0);
        pr_out[(size_t)(nq0 + 1) * 256 + col] = tanhf(acc1);
        pr_out[(size_t)(nq0 + 2) * 256 + col] = tanhf(acc2);
    } else {
        int j = col - 256;
        logit_s[0][j] = acc0;
        logit_s[1][j] = acc1;
        logit_s[2][j] = acc2;
    }
    __syncthreads();

    {
        int i = tid & 15;
        int g = tid >> 4;
        int qi = g >> 3, h = g & 7;
        float v = logit_s[qi][h * 16 + i];
        float m = v;
        #pragma unroll
        for (int off = 8; off >= 1; off >>= 1)
            m = fmaxf(m, __shfl_xor(m, off, 16));
        float e = expf(v - m);
        float s = e;
        #pragma unroll
        for (int off = 8; off >= 1; off >>= 1)
            s += __shfl_xor(s, off, 16);
        attn_out[(size_t)(nq0 + qi) * 128 + h * 16 + i] = e / s;
    }
}

// --------- K3: multi-scale deformable sampling + weighted sum ----------
__global__ __launch_bounds__(256) void k_sample(
    const float* __restrict__ value,
    const float* __restrict__ refp,
    const float* __restrict__ pr,
    const float* __restrict__ attn,
    float* __restrict__ out_attn)
{
    int nq = blockIdx.x;
    int n = nq / LQ;
    int tid = threadIdx.x;
    int h = tid >> 5, dh = tid & 31;

    float acc = 0.f;
    for (int l = 0; l < NL; ++l) {
        const float* rp = refp + ((size_t)nq * NL + l) * 4;
        float cx = rp[0], cy = rp[1], rw = rp[2], rh = rp[3];
        int Hl = d_HL[l], Wl = d_WL[l], s = d_ST[l];
        const float* vl = value + ((size_t)n * LEN_IN + s) * CDIM;

        #pragma unroll
        for (int p = 0; p < NP; ++p) {
            float prx = pr[(size_t)nq * 256 + h * 32 + l * 8 + p * 2 + 0];
            float pry = pr[(size_t)nq * 256 + h * 32 + l * 8 + p * 2 + 1];
            float a   = attn[(size_t)nq * 128 + h * 16 + l * 4 + p];
            float px = (cx + prx * rw * 0.5f) * Wl - 0.5f;
            float py = (cy + pry * rh * 0.5f) * Hl - 0.5f;
            float x0f = floorf(px), y0f = floorf(py);
            float wx1 = px - x0f, wy1 = py - y0f;
            int x0 = (int)x0f, y0 = (int)y0f;
            float sv = 0.f;
            #pragma unroll
            for (int dy = 0; dy <= 1; ++dy)
                #pragma unroll
                for (int dx = 0; dx <= 1; ++dx) {
                    int yy = y0 + dy, xx = x0 + dx;
                    if (yy >= 0 && yy < Hl && xx >= 0 && xx < Wl) {
                        float wgt = (dy ? wy1 : 1.f - wy1) * (dx ? wx1 : 1.f - wx1);
                        sv += wgt * vl[((size_t)(yy * Wl + xx)) * CDIM + h * 32 + dh];
                    }
                }
            acc += a * sv;
        }
    }
    out_attn[(size_t)nq * CDIM + tid] = acc;
}

// ---------------- K4: out = out_attn @ Wo + bo ----------------
__global__ __launch_bounds__(256) void k_out_proj(
    const float* __restrict__ x,
    const float* __restrict__ Wo,
    const float* __restrict__ bo,
    float* __restrict__ out)
{
    const int ROWS = 8;
    __shared__ float a_s[ROWS][CDIM];
    int row0 = blockIdx.x * ROWS;
    int tid = threadIdx.x;

    #pragma unroll
    for (int r = 0; r < ROWS; ++r)
        a_s[r][tid] = x[(size_t)(row0 + r) * CDIM + tid];
    __syncthreads();

    float acc[ROWS];
    #pragma unroll
    for (int r = 0; r < ROWS; ++r) acc[r] = 0.f;

    for (int k = 0; k < CDIM; k += 4) {
        float w0 = Wo[(k + 0) * CDIM + tid];
        float w1 = Wo[(k + 1) * CDIM + tid];
        float w2 = Wo[(k + 2) * CDIM + tid];
        float w3 = Wo[(k + 3) * CDIM + tid];
        #pragma unroll
        for (int r = 0; r < ROWS; ++r) {
            float4 av = *(const float4*)&a_s[r][k];
            acc[r] = fmaf(av.x, w0, fmaf(av.y, w1, fmaf(av.z, w2, fmaf(av.w, w3, acc[r]))));
        }
    }
    float b = bo[tid];
    #pragma unroll
    for (int r = 0; r < ROWS; ++r)
        out[(size_t)(row0 + r) * CDIM + tid] = acc[r] + b;
}

extern "C" void kernel_launch(void* const* d_in, const int* in_sizes, int n_in,
                              void* d_out, int out_size, void* d_ws, size_t ws_size,
                              hipStream_t stream) {
    const float* refp = (const float*)d_in[1];
    const float* inp  = (const float*)d_in[2];
    const unsigned char* mask = (const unsigned char*)d_in[5];
    const float* Wv = (const float*)d_in[6];
    const float* bv = (const float*)d_in[7];
    const float* Wp = (const float*)d_in[8];
    const float* bp = (const float*)d_in[9];
    const float* Ww = (const float*)d_in[10];
    const float* bw = (const float*)d_in[11];
    const float* Wo = (const float*)d_in[12];
    const float* bo = (const float*)d_in[13];
    float* out = (float*)d_out;

    // workspace layout
    char* ws = (char*)d_ws;
    constexpr size_t VALUE_BYTES = (size_t)NB * LEN_IN * CDIM * 4;        // 81,702,912
    constexpr size_t ROI_BYTES   = (size_t)MPAD * ROI_DIM * 2;            // 30,507,008
    constexpr size_t WT_BYTES    = (size_t)NDIM * ROI_DIM * 2;            //  9,633,792
    constexpr size_t PART_BYTES  = (size_t)GSEG * MPAD * NDIM * 4;        // 13,074,432
    constexpr size_t PR_BYTES    = (size_t)NQ_TOT * 256 * 4;
    constexpr size_t ATTN_BYTES  = (size_t)NQ_TOT * 128 * 4;
    constexpr size_t OA_BYTES    = (size_t)NQ_TOT * 256 * 4;

    size_t off = 0;
    float* value = (float*)(ws + off);           off += VALUE_BYTES;
    unsigned short* roiH = (unsigned short*)(ws + off); off += ROI_BYTES;
    unsigned short* roiL = (unsigned short*)(ws + off); off += ROI_BYTES;
    unsigned short* WTh  = (unsigned short*)(ws + off); off += WT_BYTES;
    unsigned short* WTl  = (unsigned short*)(ws + off); off += WT_BYTES;
    float* partials = (float*)(ws + off);        off += PART_BYTES;
    float* pr       = (float*)(ws + off);        off += PR_BYTES;
    float* attn     = (float*)(ws + off);        off += ATTN_BYTES;
    float* out_attn = (float*)(ws + off);        off += OA_BYTES;
    const size_t NEED_FAST = off;

    // K1: value projection
    {
        int total = NB * LEN_IN;
        int grid = (total + 15) / 16;
        k_value_proj<<<grid, 256, 0, stream>>>(inp, mask, Wv, bv, value);
    }

    if (ws_size >= NEED_FAST) {
        // K2a: ROI align -> bf16 hi/lo
        k_roi_split<<<MPAD, 256, 0, stream>>>(value, refp, roiH, roiL);
        // K2w: W transpose + split
        k_wsplit<<<dim3(ROI_DIM / 32, NDIM / 32), 256, 0, stream>>>(Wp, Ww, WTh, WTl);
        // K2b: bf16x3 MFMA GEMM, split-K
        k_gemm_bf16x3<<<dim3(MPAD / 64, NDIM / 128, GSEG), 256, 0, stream>>>(
            roiH, roiL, WTh, WTl, partials);
        // K2c: epilogue
        k_epilogue<<<NQ_TOT, 384, 0, stream>>>(partials, bp, bw, pr, attn);
    } else {
        // fallback: round-1 fused path (needs only value+pr+attn+out_attn)
        float* pr_f   = (float*)(ws + VALUE_BYTES);
        float* attn_f = (float*)(ws + VALUE_BYTES + PR_BYTES);
        pr = pr_f; attn = attn_f;
        out_attn = (float*)(ws + VALUE_BYTES + PR_BYTES + ATTN_BYTES);
        k_roi_gemm<<<NQ_TOT / QPB, 384, 0, stream>>>(value, refp, Wp, bp, Ww, bw, pr, attn);
    }

    // K3: deformable sampling
    k_sample<<<NQ_TOT, 256, 0, stream>>>(value, refp, pr, attn, out_attn);
    // K4: output projection
    k_out_proj<<<NQ_TOT / 8, 256, 0, stream>>>(out_attn, Wo, bo, out);
}

// Round 3
// 286.340 us; speedup vs baseline: 4.6864x; 1.3949x over previous
//
#include <hip/hip_runtime.h>
#include <hip/hip_bf16.h>
#include <math.h>

// Problem constants (fixed by setup_inputs)
#define NB 4
#define LQ 300
#define CDIM 256
#define NH 8
#define DH 32
#define NL 4
#define NP 4
#define ROI_ 7
#define LEN_IN 19947
#define H0 100
#define W0 150
#define ROI_DIM (ROI_*ROI_*CDIM)   // 12544
#define NQ_TOT (NB*LQ)             // 1200
#define QPB 3                      // queries per block in fallback K2

// K2b GEMM config
#define MPAD 1216                  // 19 * 64
#define NDIM 384
#define GSEG 7                     // split-K segments
#define GCH  28                    // K-chunks (of 64) per segment: 7*28*64 = 12544

// K1 GEMM config
#define VTOT (NB*LEN_IN)           // 79788
#define VMT  624                   // ceil(79788/128)

__device__ __constant__ int d_HL[4] = {100, 50, 25, 13};
__device__ __constant__ int d_WL[4] = {150, 75, 38, 19};
__device__ __constant__ int d_ST[4] = {0, 15000, 18750, 19700};

typedef __attribute__((ext_vector_type(8))) short short8;
typedef __attribute__((ext_vector_type(4))) float f32x4;

__device__ __forceinline__ unsigned short f2bf(float f) {
    unsigned int u = __float_as_uint(f);
    unsigned int r = (u + 0x7fffu + ((u >> 16) & 1u)) >> 16;
    return (unsigned short)r;
}
__device__ __forceinline__ float bf2f(unsigned short s) {
    return __uint_as_float(((unsigned int)s) << 16);
}

// ---------- K1w: transpose + bf16-split Wv (256x256) -> WvT (256x256) -------
__global__ __launch_bounds__(256) void k_wvsplit(
    const float* __restrict__ Wv,
    unsigned short* __restrict__ WvTh,
    unsigned short* __restrict__ WvTl)
{
    __shared__ float tile[32][33];
    int k0 = blockIdx.x * 32, c0 = blockIdx.y * 32;
    int tx = threadIdx.x & 31, ty = threadIdx.x >> 5;
    #pragma unroll
    for (int i = 0; i < 4; ++i)
        tile[ty + i * 8][tx] = Wv[(size_t)(k0 + ty + i * 8) * CDIM + c0 + tx];
    __syncthreads();
    #pragma unroll
    for (int i = 0; i < 4; ++i) {
        int c = c0 + ty + i * 8, k = k0 + tx;
        float v = tile[tx][ty + i * 8];
        unsigned short hb = f2bf(v);
        WvTh[(size_t)c * CDIM + k] = hb;
        WvTl[(size_t)c * CDIM + k] = f2bf(v - bf2f(hb));
    }
}

// ------- K1: value = input_flatten @ Wv + bv (bf16x3 MFMA), masked ----------
// block tile 128x128, 4 waves 2x2, wave tile 64x64, K-chunks of 64
__global__ __launch_bounds__(256) void k_value_mfma(
    const float* __restrict__ inp,            // (VTOT, 256)
    const unsigned char* __restrict__ mask,   // (VTOT)
    const unsigned short* __restrict__ WvTh,  // (256, 256)
    const unsigned short* __restrict__ WvTl,
    const float* __restrict__ bv,             // (256)
    float* __restrict__ value)                // (VTOT, 256)
{
    __shared__ unsigned short aH[128 * 64], aL[128 * 64];   // 16KB each
    __shared__ unsigned short bH[128 * 64], bL[128 * 64];   // 16KB each
    const int row0 = blockIdx.x * 128;
    const int n0 = blockIdx.y * 128;
    const int tid = threadIdx.x;
    const int lane = tid & 63;
    const int wid = tid >> 6;
    const int wm = wid >> 1, wn = wid & 1;    // wave tile 64x64
    const int lr = lane & 15, kb = lane >> 4;

    f32x4 acc[4][4];
    #pragma unroll
    for (int i = 0; i < 4; ++i)
        #pragma unroll
        for (int j = 0; j < 4; ++j) acc[i][j] = f32x4{0.f, 0.f, 0.f, 0.f};

    for (int ch = 0; ch < 4; ++ch) {
        const int k0 = ch * 64;
        __syncthreads();
        // stage A: 128 rows x 8 octets = 1024 slots, 4/thread; f32 -> hi/lo bf16
        #pragma unroll
        for (int i = 0; i < 4; ++i) {
            int slot = tid + i * 256;
            int row = slot >> 3, ko = slot & 7;
            int grow = row0 + row;
            if (grow >= VTOT) grow = VTOT - 1;
            const float* src = inp + (size_t)grow * CDIM + k0 + ko * 8;
            float4 v0 = *(const float4*)src;
            float4 v1 = *(const float4*)(src + 4);
            float f[8] = {v0.x, v0.y, v0.z, v0.w, v1.x, v1.y, v1.z, v1.w};
            short8 h, l;
            #pragma unroll
            for (int e = 0; e < 8; ++e) {
                unsigned short hb = f2bf(f[e]);
                h[e] = (short)hb;
                l[e] = (short)f2bf(f[e] - bf2f(hb));
            }
            int off = (row * 128 + ko * 16) ^ ((row & 7) << 4);
            *(short8*)((char*)aH + off) = h;
            *(short8*)((char*)aL + off) = l;
        }
        // stage B: 128 cols x 8 octets = 1024 slots, 4/thread (pre-split bf16)
        #pragma unroll
        for (int i = 0; i < 4; ++i) {
            int slot = tid + i * 256;
            int col = slot >> 3, ko = slot & 7;
            size_t g = (size_t)(n0 + col) * CDIM + k0 + ko * 8;
            int off = (col * 128 + ko * 16) ^ ((col & 7) << 4);
            *(short8*)((char*)bH + off) = *(const short8*)(WvTh + g);
            *(short8*)((char*)bL + off) = *(const short8*)(WvTl + g);
        }
        __syncthreads();
        #pragma unroll
        for (int kk = 0; kk < 2; ++kk) {
            short8 ah[4], al[4], bh[4], bl[4];
            #pragma unroll
            for (int i = 0; i < 4; ++i) {
                int row = wm * 64 + i * 16 + lr;
                int off = (row * 128 + (kk * 32 + kb * 8) * 2) ^ ((row & 7) << 4);
                ah[i] = *(const short8*)((const char*)aH + off);
                al[i] = *(const short8*)((const char*)aL + off);
            }
            #pragma unroll
            for (int j = 0; j < 4; ++j) {
                int col = wn * 64 + j * 16 + lr;
                int off = (col * 128 + (kk * 32 + kb * 8) * 2) ^ ((col & 7) << 4);
                bh[j] = *(const short8*)((const char*)bH + off);
                bl[j] = *(const short8*)((const char*)bL + off);
            }
            #pragma unroll
            for (int i = 0; i < 4; ++i)
                #pragma unroll
                for (int j = 0; j < 4; ++j) {
                    acc[i][j] = __builtin_amdgcn_mfma_f32_16x16x32_bf16(ah[i], bh[j], acc[i][j], 0, 0, 0);
                    acc[i][j] = __builtin_amdgcn_mfma_f32_16x16x32_bf16(ah[i], bl[j], acc[i][j], 0, 0, 0);
                    acc[i][j] = __builtin_amdgcn_mfma_f32_16x16x32_bf16(al[i], bh[j], acc[i][j], 0, 0, 0);
                }
        }
    }

    // epilogue: bias + mask + store
    #pragma unroll
    for (int j = 0; j < 4; ++j) {
        int c = n0 + wn * 64 + j * 16 + lr;
        float b = bv[c];
        #pragma unroll
        for (int i = 0; i < 4; ++i) {
            int q = row0 + wm * 64 + i * 16 + (lane >> 4) * 4;
            #pragma unroll
            for (int e = 0; e < 4; ++e) {
                int row = q + e;
                if (row < VTOT) {
                    float v = acc[i][j][e] + b;
                    if (mask[row]) v = 0.f;
                    value[(size_t)row * CDIM + c] = v;
                }
            }
        }
    }
}

// ----------- FALLBACK K1 (round-2 VALU version, if ws too small) ------------
__global__ __launch_bounds__(256) void k_value_proj(
    const float* __restrict__ inp,
    const unsigned char* __restrict__ mask,
    const float* __restrict__ Wv,
    const float* __restrict__ bv,
    float* __restrict__ value)
{
    const int ROWS = 16;
    __shared__ float a_s[ROWS][CDIM];
    const int total = VTOT;
    int row0 = blockIdx.x * ROWS;
    int tid = threadIdx.x;

    #pragma unroll
    for (int r = 0; r < ROWS; ++r) {
        int row = row0 + r;
        a_s[r][tid] = (row < total) ? inp[(size_t)row * CDIM + tid] : 0.f;
    }
    __syncthreads();

    float acc[ROWS];
    #pragma unroll
    for (int r = 0; r < ROWS; ++r) acc[r] = 0.f;

    for (int k = 0; k < CDIM; k += 4) {
        float w0 = Wv[(k + 0) * CDIM + tid];
        float w1 = Wv[(k + 1) * CDIM + tid];
        float w2 = Wv[(k + 2) * CDIM + tid];
        float w3 = Wv[(k + 3) * CDIM + tid];
        #pragma unroll
        for (int r = 0; r < ROWS; ++r) {
            float4 av = *(const float4*)&a_s[r][k];
            acc[r] = fmaf(av.x, w0, fmaf(av.y, w1, fmaf(av.z, w2, fmaf(av.w, w3, acc[r]))));
        }
    }

    float b = bv[tid];
    #pragma unroll
    for (int r = 0; r < ROWS; ++r) {
        int row = row0 + r;
        if (row < total) {
            float v = acc[r] + b;
            if (mask[row]) v = 0.f;
            value[(size_t)row * CDIM + tid] = v;
        }
    }
}

// -------- K2a: ROI-align (level 0) -> roi_hi / roi_lo (bf16 split) ----------
__global__ __launch_bounds__(256) void k_roi_split(
    const float* __restrict__ value,
    const float* __restrict__ refp,
    unsigned short* __restrict__ roiH,
    unsigned short* __restrict__ roiL)
{
    int q = blockIdx.x;
    int tid = threadIdx.x;
    if (q >= NQ_TOT) {
        for (int i = 0; i < 49; ++i) {
            roiH[(size_t)q * ROI_DIM + i * 256 + tid] = 0;
            roiL[(size_t)q * ROI_DIM + i * 256 + tid] = 0;
        }
        return;
    }
    int n = q / LQ;
    const float* rp = refp + (size_t)q * NL * 4;
    float cx = rp[0], cy = rp[1], w = rp[2], h = rp[3];
    float x1 = (cx - 0.5f * w) * W0 - 0.5f;
    float y1 = (cy - 0.5f * h) * H0 - 0.5f;
    float binw = w * W0 / ROI_;
    float binh = h * H0 / ROI_;
    const float* v0 = value + (size_t)n * LEN_IN * CDIM;

    for (int i = 0; i < 49; ++i) {
        int r = i / ROI_, c = i % ROI_;
        float sy = y1 + binh * (r + 0.5f);
        float sx = x1 + binw * (c + 0.5f);
        float y0f = floorf(sy), x0f = floorf(sx);
        float wy1 = sy - y0f, wx1 = sx - x0f;
        int y0 = (int)y0f, x0 = (int)x0f;
        float acc = 0.f;
        #pragma unroll
        for (int dy = 0; dy <= 1; ++dy) {
            #pragma unroll
            for (int dx = 0; dx <= 1; ++dx) {
                int yy = y0 + dy, xx = x0 + dx;
                if (yy >= 0 && yy < H0 && xx >= 0 && xx < W0) {
                    float wgt = (dy ? wy1 : 1.f - wy1) * (dx ? wx1 : 1.f - wx1);
                    acc += wgt * v0[((size_t)(yy * W0 + xx)) * CDIM + tid];
                }
            }
        }
        unsigned short hb = f2bf(acc);
        float rem = acc - bf2f(hb);
        roiH[(size_t)q * ROI_DIM + i * 256 + tid] = hb;
        roiL[(size_t)q * ROI_DIM + i * 256 + tid] = f2bf(rem);
    }
}

// ------ K2w: transpose + bf16-split [Wp|Ww] (12544x384) -> WT (384x12544) ----
__global__ __launch_bounds__(256) void k_wsplit(
    const float* __restrict__ Wp,
    const float* __restrict__ Ww,
    unsigned short* __restrict__ WTh,
    unsigned short* __restrict__ WTl)
{
    __shared__ float tile[32][33];
    int k0 = blockIdx.x * 32, c0 = blockIdx.y * 32;
    int tx = threadIdx.x & 31, ty = threadIdx.x >> 5;

    #pragma unroll
    for (int i = 0; i < 4; ++i) {
        int k = k0 + ty + i * 8, c = c0 + tx;
        float v = (c < 256) ? Wp[(size_t)k * 256 + c] : Ww[(size_t)k * 128 + (c - 256)];
        tile[ty + i * 8][tx] = v;
    }
    __syncthreads();
    #pragma unroll
    for (int i = 0; i < 4; ++i) {
        int c = c0 + ty + i * 8, k = k0 + tx;
        float v = tile[tx][ty + i * 8];
        unsigned short hb = f2bf(v);
        float rem = v - bf2f(hb);
        WTh[(size_t)c * ROI_DIM + k] = hb;
        WTl[(size_t)c * ROI_DIM + k] = f2bf(rem);
    }
}

// ------------- K2b: bf16x3 MFMA GEMM (MPAD x 384 x 12544), split-K -----------
__global__ __launch_bounds__(256) void k_gemm_bf16x3(
    const unsigned short* __restrict__ roiH,
    const unsigned short* __restrict__ roiL,
    const unsigned short* __restrict__ WTh,
    const unsigned short* __restrict__ WTl,
    float* __restrict__ partials)      // (GSEG, MPAD, 384)
{
    __shared__ unsigned short aH[64 * 64], aL[64 * 64];
    __shared__ unsigned short bH[128 * 64], bL[128 * 64];
    const int mt = blockIdx.x, nt = blockIdx.y, seg = blockIdx.z;
    const int q0 = mt * 64, c0 = nt * 128;
    const int tid = threadIdx.x;
    const int lane = tid & 63;
    const int wid = tid >> 6;
    const int wm = wid >> 1, wn = wid & 1;
    const int lr = lane & 15, kb = lane >> 4;

    f32x4 acc[2][4];
    #pragma unroll
    for (int i = 0; i < 2; ++i)
        #pragma unroll
        for (int j = 0; j < 4; ++j) acc[i][j] = f32x4{0.f, 0.f, 0.f, 0.f};

    const int kseg0 = seg * (GCH * 64);

    for (int ch = 0; ch < GCH; ++ch) {
        const int k0 = kseg0 + ch * 64;
        __syncthreads();
        #pragma unroll
        for (int i = 0; i < 2; ++i) {
            int slot = tid + i * 256;
            int row = slot >> 3, ko = slot & 7;
            size_t g = (size_t)(q0 + row) * ROI_DIM + k0 + ko * 8;
            int off = (row * 128 + ko * 16) ^ ((row & 7) << 4);
            *(short8*)((char*)aH + off) = *(const short8*)(roiH + g);
            *(short8*)((char*)aL + off) = *(const short8*)(roiL + g);
        }
        #pragma unroll
        for (int i = 0; i < 4; ++i) {
            int slot = tid + i * 256;
            int col = slot >> 3, ko = slot & 7;
            size_t g = (size_t)(c0 + col) * ROI_DIM + k0 + ko * 8;
            int off = (col * 128 + ko * 16) ^ ((col & 7) << 4);
            *(short8*)((char*)bH + off) = *(const short8*)(WTh + g);
            *(short8*)((char*)bL + off) = *(const short8*)(WTl + g);
        }
        __syncthreads();
        #pragma unroll
        for (int kk = 0; kk < 2; ++kk) {
            short8 ah[2], al[2], bh[4], bl[4];
            #pragma unroll
            for (int i = 0; i < 2; ++i) {
                int row = wm * 32 + i * 16 + lr;
                int off = (row * 128 + (kk * 32 + kb * 8) * 2) ^ ((row & 7) << 4);
                ah[i] = *(const short8*)((const char*)aH + off);
                al[i] = *(const short8*)((const char*)aL + off);
            }
            #pragma unroll
            for (int j = 0; j < 4; ++j) {
                int col = wn * 64 + j * 16 + lr;
                int off = (col * 128 + (kk * 32 + kb * 8) * 2) ^ ((col & 7) << 4);
                bh[j] = *(const short8*)((const char*)bH + off);
                bl[j] = *(const short8*)((const char*)bL + off);
            }
            #pragma unroll
            for (int i = 0; i < 2; ++i)
                #pragma unroll
                for (int j = 0; j < 4; ++j) {
                    acc[i][j] = __builtin_amdgcn_mfma_f32_16x16x32_bf16(ah[i], bh[j], acc[i][j], 0, 0, 0);
                    acc[i][j] = __builtin_amdgcn_mfma_f32_16x16x32_bf16(ah[i], bl[j], acc[i][j], 0, 0, 0);
                    acc[i][j] = __builtin_amdgcn_mfma_f32_16x16x32_bf16(al[i], bh[j], acc[i][j], 0, 0, 0);
                }
        }
    }

    #pragma unroll
    for (int i = 0; i < 2; ++i)
        #pragma unroll
        for (int j = 0; j < 4; ++j) {
            int q = q0 + wm * 32 + i * 16 + (lane >> 4) * 4;
            int c = c0 + wn * 64 + j * 16 + lr;
            #pragma unroll
            for (int e = 0; e < 4; ++e)
                partials[((size_t)seg * MPAD + q + e) * NDIM + c] = acc[i][j][e];
        }
}

// ---------- K2c: reduce partials + bias; tanh offsets; softmax weights -------
__global__ __launch_bounds__(384) void k_epilogue(
    const float* __restrict__ partials,
    const float* __restrict__ bp, const float* __restrict__ bw,
    float* __restrict__ pr,
    float* __restrict__ attn)
{
    __shared__ float logit_s[128];
    int q = blockIdx.x;
    int t = threadIdx.x;
    float s = 0.f;
    #pragma unroll
    for (int g = 0; g < GSEG; ++g)
        s += partials[((size_t)g * MPAD + q) * NDIM + t];
    if (t < 256) {
        pr[(size_t)q * 256 + t] = tanhf(s + bp[t]);
    } else {
        logit_s[t - 256] = s + bw[t - 256];
    }
    __syncthreads();
    if (t < 128) {
        float v = logit_s[t];
        float m = v;
        #pragma unroll
        for (int off = 8; off >= 1; off >>= 1)
            m = fmaxf(m, __shfl_xor(m, off, 16));
        float e = expf(v - m);
        float sum = e;
        #pragma unroll
        for (int off = 8; off >= 1; off >>= 1)
            sum += __shfl_xor(sum, off, 16);
        attn[(size_t)q * 128 + t] = e / sum;
    }
}

// ------- FALLBACK K2 (round-1 fused kernel) used only if ws too small -------
__global__ __launch_bounds__(384) void k_roi_gemm(
    const float* __restrict__ value,
    const float* __restrict__ refp,
    const float* __restrict__ Wp,
    const float* __restrict__ bp,
    const float* __restrict__ Ww,
    const float* __restrict__ bw,
    float* __restrict__ pr_out,
    float* __restrict__ attn_out)
{
    __shared__ float roi_s[QPB][ROI_DIM];
    __shared__ float logit_s[QPB][128];

    int tid = threadIdx.x;
    int nq0 = blockIdx.x * QPB;

    for (int qi = 0; qi < QPB; ++qi) {
        int nq = nq0 + qi;
        int n = nq / LQ;
        const float* rp = refp + (size_t)nq * NL * 4;
        float cx = rp[0], cy = rp[1], w = rp[2], h = rp[3];
        float x1 = (cx - 0.5f * w) * W0 - 0.5f;
        float y1 = (cy - 0.5f * h) * H0 - 0.5f;
        float binw = w * W0 / ROI_;
        float binh = h * H0 / ROI_;
        const float* v0 = value + (size_t)n * LEN_IN * CDIM;

        for (int e = tid; e < ROI_DIM; e += 384) {
            int p = e >> 8;
            int ch = e & 255;
            int r = p / ROI_, c = p % ROI_;
            float sy = y1 + binh * (r + 0.5f);
            float sx = x1 + binw * (c + 0.5f);
            float y0f = floorf(sy), x0f = floorf(sx);
            float wy1 = sy - y0f, wx1 = sx - x0f;
            int y0 = (int)y0f, x0 = (int)x0f;
            float acc = 0.f;
            #pragma unroll
            for (int dy = 0; dy <= 1; ++dy)
                #pragma unroll
                for (int dx = 0; dx <= 1; ++dx) {
                    int yy = y0 + dy, xx = x0 + dx;
                    if (yy >= 0 && yy < H0 && xx >= 0 && xx < W0) {
                        float wgt = (dy ? wy1 : 1.f - wy1) * (dx ? wx1 : 1.f - wx1);
                        acc += wgt * v0[((size_t)(yy * W0 + xx)) * CDIM + ch];
                    }
                }
            roi_s[qi][e] = acc;
        }
    }
    __syncthreads();

    int col = tid;
    const float* Wsel;
    int stride;
    float bias;
    if (col < 256) { Wsel = Wp + col;         stride = 256; bias = bp[col]; }
    else           { Wsel = Ww + (col - 256); stride = 128; bias = bw[col - 256]; }

    float acc0 = 0.f, acc1 = 0.f, acc2 = 0.f;
    const float* wptr = Wsel;
    #pragma unroll 8
    for (int k = 0; k < ROI_DIM; ++k) {
        float wv = *wptr; wptr += stride;
        acc0 += roi_s[0][k] * wv;
        acc1 += roi_s[1][k] * wv;
        acc2 += roi_s[2][k] * wv;
    }
    acc0 += bias; acc1 += bias; acc2 += bias;

    if (col < 256) {
        pr_out[(size_t)(nq0 + 0) * 256 + col] = tanhf(acc0);
        pr_out[(size_t)(nq0 + 1) * 256 + col] = tanhf(acc1);
        pr_out[(size_t)(nq0 + 2) * 256 + col] = tanhf(acc2);
    } else {
        int j = col - 256;
        logit_s[0][j] = acc0;
        logit_s[1][j] = acc1;
        logit_s[2][j] = acc2;
    }
    __syncthreads();

    {
        int i = tid & 15;
        int g = tid >> 4;
        int qi = g >> 3, h = g & 7;
        float v = logit_s[qi][h * 16 + i];
        float m = v;
        #pragma unroll
        for (int off = 8; off >= 1; off >>= 1)
            m = fmaxf(m, __shfl_xor(m, off, 16));
        float e = expf(v - m);
        float s = e;
        #pragma unroll
        for (int off = 8; off >= 1; off >>= 1)
            s += __shfl_xor(s, off, 16);
        attn_out[(size_t)(nq0 + qi) * 128 + h * 16 + i] = e / s;
    }
}

// --------- K3: multi-scale deformable sampling + weighted sum ----------
__global__ __launch_bounds__(256) void k_sample(
    const float* __restrict__ value,
    const float* __restrict__ refp,
    const float* __restrict__ pr,
    const float* __restrict__ attn,
    float* __restrict__ out_attn)
{
    int nq = blockIdx.x;
    int n = nq / LQ;
    int tid = threadIdx.x;
    int h = tid >> 5, dh = tid & 31;

    float acc = 0.f;
    for (int l = 0; l < NL; ++l) {
        const float* rp = refp + ((size_t)nq * NL + l) * 4;
        float cx = rp[0], cy = rp[1], rw = rp[2], rh = rp[3];
        int Hl = d_HL[l], Wl = d_WL[l], s = d_ST[l];
        const float* vl = value + ((size_t)n * LEN_IN + s) * CDIM;

        #pragma unroll
        for (int p = 0; p < NP; ++p) {
            float prx = pr[(size_t)nq * 256 + h * 32 + l * 8 + p * 2 + 0];
            float pry = pr[(size_t)nq * 256 + h * 32 + l * 8 + p * 2 + 1];
            float a   = attn[(size_t)nq * 128 + h * 16 + l * 4 + p];
            float px = (cx + prx * rw * 0.5f) * Wl - 0.5f;
            float py = (cy + pry * rh * 0.5f) * Hl - 0.5f;
            float x0f = floorf(px), y0f = floorf(py);
            float wx1 = px - x0f, wy1 = py - y0f;
            int x0 = (int)x0f, y0 = (int)y0f;
            float sv = 0.f;
            #pragma unroll
            for (int dy = 0; dy <= 1; ++dy)
                #pragma unroll
                for (int dx = 0; dx <= 1; ++dx) {
                    int yy = y0 + dy, xx = x0 + dx;
                    if (yy >= 0 && yy < Hl && xx >= 0 && xx < Wl) {
                        float wgt = (dy ? wy1 : 1.f - wy1) * (dx ? wx1 : 1.f - wx1);
                        sv += wgt * vl[((size_t)(yy * Wl + xx)) * CDIM + h * 32 + dh];
                    }
                }
            acc += a * sv;
        }
    }
    out_attn[(size_t)nq * CDIM + tid] = acc;
}

// ---------------- K4: out = out_attn @ Wo + bo ----------------
__global__ __launch_bounds__(256) void k_out_proj(
    const float* __restrict__ x,
    const float* __restrict__ Wo,
    const float* __restrict__ bo,
    float* __restrict__ out)
{
    const int ROWS = 8;
    __shared__ float a_s[ROWS][CDIM];
    int row0 = blockIdx.x * ROWS;
    int tid = threadIdx.x;

    #pragma unroll
    for (int r = 0; r < ROWS; ++r)
        a_s[r][tid] = x[(size_t)(row0 + r) * CDIM + tid];
    __syncthreads();

    float acc[ROWS];
    #pragma unroll
    for (int r = 0; r < ROWS; ++r) acc[r] = 0.f;

    for (int k = 0; k < CDIM; k += 4) {
        float w0 = Wo[(k + 0) * CDIM + tid];
        float w1 = Wo[(k + 1) * CDIM + tid];
        float w2 = Wo[(k + 2) * CDIM + tid];
        float w3 = Wo[(k + 3) * CDIM + tid];
        #pragma unroll
        for (int r = 0; r < ROWS; ++r) {
            float4 av = *(const float4*)&a_s[r][k];
            acc[r] = fmaf(av.x, w0, fmaf(av.y, w1, fmaf(av.z, w2, fmaf(av.w, w3, acc[r]))));
        }
    }
    float b = bo[tid];
    #pragma unroll
    for (int r = 0; r < ROWS; ++r)
        out[(size_t)(row0 + r) * CDIM + tid] = acc[r] + b;
}

extern "C" void kernel_launch(void* const* d_in, const int* in_sizes, int n_in,
                              void* d_out, int out_size, void* d_ws, size_t ws_size,
                              hipStream_t stream) {
    const float* refp = (const float*)d_in[1];
    const float* inp  = (const float*)d_in[2];
    const unsigned char* mask = (const unsigned char*)d_in[5];
    const float* Wv = (const float*)d_in[6];
    const float* bv = (const float*)d_in[7];
    const float* Wp = (const float*)d_in[8];
    const float* bp = (const float*)d_in[9];
    const float* Ww = (const float*)d_in[10];
    const float* bw = (const float*)d_in[11];
    const float* Wo = (const float*)d_in[12];
    const float* bo = (const float*)d_in[13];
    float* out = (float*)d_out;

    // workspace layout
    char* ws = (char*)d_ws;
    constexpr size_t VALUE_BYTES = (size_t)VTOT * CDIM * 4;               // 81,702,912
    constexpr size_t ROI_BYTES   = (size_t)MPAD * ROI_DIM * 2;            // 30,507,008
    constexpr size_t WT_BYTES    = (size_t)NDIM * ROI_DIM * 2;            //  9,633,792
    constexpr size_t WVT_BYTES   = (size_t)CDIM * CDIM * 2;               //    131,072
    constexpr size_t PART_BYTES  = (size_t)GSEG * MPAD * NDIM * 4;        // 13,074,432
    constexpr size_t PR_BYTES    = (size_t)NQ_TOT * 256 * 4;
    constexpr size_t ATTN_BYTES  = (size_t)NQ_TOT * 128 * 4;
    constexpr size_t OA_BYTES    = (size_t)NQ_TOT * 256 * 4;

    size_t off = 0;
    float* value = (float*)(ws + off);                  off += VALUE_BYTES;
    unsigned short* roiH = (unsigned short*)(ws + off); off += ROI_BYTES;
    unsigned short* roiL = (unsigned short*)(ws + off); off += ROI_BYTES;
    unsigned short* WTh  = (unsigned short*)(ws + off); off += WT_BYTES;
    unsigned short* WTl  = (unsigned short*)(ws + off); off += WT_BYTES;
    unsigned short* WvTh = (unsigned short*)(ws + off); off += WVT_BYTES;
    unsigned short* WvTl = (unsigned short*)(ws + off); off += WVT_BYTES;
    float* partials = (float*)(ws + off);               off += PART_BYTES;
    float* pr       = (float*)(ws + off);               off += PR_BYTES;
    float* attn     = (float*)(ws + off);               off += ATTN_BYTES;
    float* out_attn = (float*)(ws + off);               off += OA_BYTES;
    const size_t NEED_FAST = off;

    if (ws_size >= NEED_FAST) {
        // K1: Wv split + MFMA value projection
        k_wvsplit<<<dim3(CDIM / 32, CDIM / 32), 256, 0, stream>>>(Wv, WvTh, WvTl);
        k_value_mfma<<<dim3(VMT, 2), 256, 0, stream>>>(inp, mask, WvTh, WvTl, bv, value);
        // K2a: ROI align -> bf16 hi/lo
        k_roi_split<<<MPAD, 256, 0, stream>>>(value, refp, roiH, roiL);
        // K2w: W transpose + split
        k_wsplit<<<dim3(ROI_DIM / 32, NDIM / 32), 256, 0, stream>>>(Wp, Ww, WTh, WTl);
        // K2b: bf16x3 MFMA GEMM, split-K
        k_gemm_bf16x3<<<dim3(MPAD / 64, NDIM / 128, GSEG), 256, 0, stream>>>(
            roiH, roiL, WTh, WTl, partials);
        // K2c: epilogue
        k_epilogue<<<NQ_TOT, 384, 0, stream>>>(partials, bp, bw, pr, attn);
    } else {
        // fallback: round-1/2 path
        int total = VTOT;
        k_value_proj<<<(total + 15) / 16, 256, 0, stream>>>(inp, mask, Wv, bv, value);
        float* pr_f   = (float*)(ws + VALUE_BYTES);
        float* attn_f = (float*)(ws + VALUE_BYTES + PR_BYTES);
        pr = pr_f; attn = attn_f;
        out_attn = (float*)(ws + VALUE_BYTES + PR_BYTES + ATTN_BYTES);
        k_roi_gemm<<<NQ_TOT / QPB, 384, 0, stream>>>(value, refp, Wp, bp, Ww, bw, pr, attn);
    }

    // K3: deformable sampling
    k_sample<<<NQ_TOT, 256, 0, stream>>>(value, refp, pr, attn, out_attn);
    // K4: output projection
    k_out_proj<<<NQ_TOT / 8, 256, 0, stream>>>(out_attn, Wo, bo, out);
}